// Round 2
// 68.049 us; speedup vs baseline: 1.0338x; 1.0338x over previous
//
#include <hip/hip_runtime.h>

#define NQ  4
#define DIM 16

// ---------------------------------------------------------------------------
// Fully fused kernel. Each block:
//   1) Wave-parallel sim of the shared unitary U: thread (j=tid>>4, m=tid&15)
//      holds element U[m][j]; RZ/RY butterflies via __shfl_xor(.., bit)
//      (partner tid^bit is in-wave since bit<=8<64). CNOT = shfl_xor(4)+select.
//   2) [tid<32]  w[o][m] = sum_i head_w[o,i] * (bit_i(m) ? -1 : +1)
//   3) [all 256] A_o[j][k] = sum_m w[o][m] * Re(conj(U[m][j]) U[m][k])
//   4) [tid<162] T[o][a0..a3] = (1/16) sum_j sign(j,a) A_o[j][j^xm]; +head_b
//   Then each thread pulls all 162 T values into VGPRs (41 uniform
//   ds_read_b128 broadcasts, conflict-free) and evaluates 4 samples
//   (grid-strided, coalesced). Single launch; d_ws unused.
// ---------------------------------------------------------------------------

__device__ __forceinline__ float2 qeval_reg(const float4 xv, const float* Tr)
{
    float c0, s0, c1, s1, c2, s2, c3, s3;
    __sincosf(xv.x, &s0, &c0);
    __sincosf(xv.y, &s1, &c1);
    __sincosf(xv.z, &s2, &c2);
    __sincosf(xv.w, &s3, &c3);

    float r[2];
    #pragma unroll
    for (int o = 0; o < 2; ++o) {
        float w3[27];
        #pragma unroll
        for (int t = 0; t < 27; ++t)
            w3[t] = fmaf(s3, Tr[o * 81 + 3 * t + 2],
                    fmaf(c3, Tr[o * 81 + 3 * t + 1], Tr[o * 81 + 3 * t + 0]));
        float w2[9];
        #pragma unroll
        for (int t = 0; t < 9; ++t)
            w2[t] = fmaf(s2, w3[3 * t + 2], fmaf(c2, w3[3 * t + 1], w3[3 * t + 0]));
        float w1[3];
        #pragma unroll
        for (int t = 0; t < 3; ++t)
            w1[t] = fmaf(s1, w2[3 * t + 2], fmaf(c1, w2[3 * t + 1], w2[3 * t + 0]));
        r[o] = fmaf(s0, w1[2], fmaf(c0, w1[1], w1[0]));
    }
    return make_float2(r[0], r[1]);
}

__global__ __launch_bounds__(256, 2) void fused_kernel(
    const float4* __restrict__ x4,       // (Btot) float4 = (B,4) floats
    const float*  __restrict__ weights,  // (2,4,4); only [0,i,0:2] used
    const float*  __restrict__ head_w,   // (2,4)
    const float*  __restrict__ head_b,   // (2,)
    float2*       __restrict__ out2,     // (Btot) float2
    const int Btot)
{
    __shared__ float Ure[DIM][DIM];      // U[m][j]
    __shared__ float Uim[DIM][DIM];
    __shared__ float sw2[2][DIM];
    __shared__ float sA[2][DIM][DIM];
    __shared__ __align__(16) float sT[164];

    const int tid = threadIdx.x;
    const int j = tid >> 4;              // column 0..15
    const int m = tid & 15;              // row    0..15

    // ---- stage 1: wave-parallel unitary sim (all 256 threads) ----
    {
        float szv[NQ], czv[NQ], syv[NQ], cyv[NQ];
        #pragma unroll
        for (int i = 0; i < NQ; ++i) {
            __sincosf(0.5f * weights[i * 4 + 0], &szv[i], &czv[i]);
            __sincosf(0.5f * weights[i * 4 + 1], &syv[i], &cyv[i]);
        }
        float sre = (m == j) ? 1.f : 0.f;
        float sim = 0.f;
        #pragma unroll
        for (int rep = 0; rep < 2; ++rep) {
            #pragma unroll
            for (int i = 0; i < NQ; ++i) {
                const int bit = 8 >> i;          // wire 0 is MSB
                const bool hi = (m & bit) != 0;
                const float cz = czv[i], sz = szv[i];
                const float cy = cyv[i], sy = syv[i];
                // RZ: lo *= e^{-i t/2}, hi *= e^{+i t/2}
                const float e = hi ? -sz : sz;
                const float zre = fmaf( e, sim, sre * cz);
                const float zim = fmaf(-e, sre, sim * cz);
                // exchange RZ'd values with butterfly partner (uniform exec)
                const float pzre = __shfl_xor(zre, bit);
                const float pzim = __shfl_xor(zim, bit);
                // RY: new_lo = cy*z_lo - sy*z_hi ; new_hi = sy*z_lo + cy*z_hi
                const float f = hi ? sy : -sy;
                sre = fmaf(f, pzre, cy * zre);
                sim = fmaf(f, pzim, cy * zim);
            }
            // CNOT(wire0 -> wire1): within bit8=1, swap bit4 pairs
            const float pre = __shfl_xor(sre, 4);
            const float pim = __shfl_xor(sim, 4);
            if (m & 8) { sre = pre; sim = pim; }
        }
        Ure[m][j] = sre;
        Uim[m][j] = sim;
    }
    // ---- stage 2: w[o][m] ----
    if (tid < 32) {
        const int o = tid >> 4, mm = tid & 15;
        float w = 0.f;
        #pragma unroll
        for (int i = 0; i < NQ; ++i) {
            const float hw = head_w[o * 4 + i];
            w += ((mm >> (3 - i)) & 1) ? -hw : hw;
        }
        sw2[o][mm] = w;
    }
    __syncthreads();

    // ---- stage 3: A (512 entries over 256 threads) ----
    #pragma unroll
    for (int it = 0; it < 2; ++it) {
        const int idx = it * 256 + tid;
        const int o  = idx >> 8;
        const int jj = (idx >> 4) & 15;
        const int kk = idx & 15;
        float acc = 0.f;
        #pragma unroll
        for (int mm = 0; mm < DIM; ++mm)
            acc = fmaf(sw2[o][mm],
                       Ure[mm][jj] * Ure[mm][kk] + Uim[mm][jj] * Uim[mm][kk], acc);
        sA[o][jj][kk] = acc;
    }
    __syncthreads();

    // ---- stage 4: T (162 entries) ----
    if (tid < 2 * 81) {
        const int o  = tid / 81;
        const int r  = tid % 81;
        const int a0 = r / 27, a1 = (r / 9) % 3, a2 = (r / 3) % 3, a3 = r % 3;
        const int xm = ((a0 == 2) << 3) | ((a1 == 2) << 2) | ((a2 == 2) << 1) | (a3 == 2);
        const int sm = ((a0 == 1) << 3) | ((a1 == 1) << 2) | ((a2 == 1) << 1) | (a3 == 1);
        float acc = 0.f;
        #pragma unroll
        for (int jj = 0; jj < DIM; ++jj) {
            const float sgn = (__popc(jj & sm) & 1) ? -1.f : 1.f;
            acc += sgn * sA[o][jj][jj ^ xm];
        }
        float t = acc * 0.0625f;
        if (r == 0) t += head_b[o];
        sT[tid] = t;
    }
    if (tid >= 162 && tid < 164) sT[tid] = 0.f;   // pad for b128 loads
    __syncthreads();

    // ---- pull T into registers: 41 uniform ds_read_b128 broadcasts ----
    float Tr[164];
    {
        const float4* sT4 = reinterpret_cast<const float4*>(sT);
        #pragma unroll
        for (int q = 0; q < 41; ++q) {
            const float4 v = sT4[q];
            Tr[4 * q + 0] = v.x;
            Tr[4 * q + 1] = v.y;
            Tr[4 * q + 2] = v.z;
            Tr[4 * q + 3] = v.w;
        }
    }

    // ---- main: 4 samples/thread, grid-strided (coalesced) ----
    const int GT   = gridDim.x << 8;        // total threads
    const int base = (blockIdx.x << 8) + tid;
    #pragma unroll 1
    for (int k = 0; k < 4; ++k) {
        const int s = base + k * GT;
        if (s < Btot) {
            const float4 xv = x4[s];
            out2[s] = qeval_reg(xv, Tr);
        }
    }
}

extern "C" void kernel_launch(void* const* d_in, const int* in_sizes, int n_in,
                              void* d_out, int out_size, void* d_ws, size_t ws_size,
                              hipStream_t stream) {
    const float* x       = (const float*)d_in[0];   // (B,4)
    const float* weights = (const float*)d_in[1];   // (2,4,4)
    const float* head_w  = (const float*)d_in[2];   // (2,4)
    const float* head_b  = (const float*)d_in[3];   // (2,)
    float* out = (float*)d_out;
    (void)d_ws; (void)ws_size;

    const int Btot   = in_sizes[0] / 4;             // samples
    const int blocks = (Btot + 1023) / 1024;        // 256 thr x 4 samples/thr

    fused_kernel<<<blocks, 256, 0, stream>>>(
        (const float4*)x, weights, head_w, head_b, (float2*)out, Btot);
}